// Round 8
// baseline (471.263 us; speedup 1.0000x reference)
//
#include <hip/hip_runtime.h>

// ---------------------------------------------------------------------------
// GCN: out = spmm(A, relu(spmm(A, x)@w1 + b1)) @ w2 + b2
// Reordered: y1 = x@w1 ; h1 = relu(spmm(y1)+b1) ; y2 = h1@w2 ; out = spmm(y2)+b2
// R13: R12's reg-staged wide-gather pipeline with the scratch-spill fixed:
//   chunk body is a MACRO expanded in the scope of the named register arrays
//   gA/gB (no pointer passing -> no address-taken arrays -> SROA promotes).
//   R12 proof of damage: VGPR=68 + WRITE_SIZE 504MB (scratch). Dataflow
//   itself verified correct (absmax 0.25) and fabric showed 4.1 TB/s.
// ---------------------------------------------------------------------------

typedef __bf16 v8bf __attribute__((ext_vector_type(8)));
typedef float  v4f  __attribute__((ext_vector_type(4)));
typedef unsigned v2u __attribute__((ext_vector_type(2)));

#define AS3 __attribute__((address_space(3)))

#define MAXB 800  // max buckets (N<=102400)

__device__ __forceinline__ unsigned short f2bf(float f) {
    unsigned u = __float_as_uint(f);
    unsigned r = u + 0x7fffu + ((u >> 16) & 1u);   // RNE
    return (unsigned short)(r >> 16);
}

__device__ __forceinline__ unsigned ldsaddr(const void* p) {
    return (unsigned)(unsigned long long)(const AS3 char*)p;
}

// HW transpose read (cooperative per 16-lane group): the group's 16 8-B slots
// form a 128-B 4x16 bf16 tile; lane receives column = its slot index.
__device__ __forceinline__ v2u tr16(unsigned a) {
    v2u d;
    asm volatile("ds_read_b64_tr_b16 %0, %1" : "=v"(d) : "v"(a));
    return d;
}

// ---- hist + prep: bucket histogram, weight casts, sentinels ---------------
__global__ __launch_bounds__(256) void hist_prep(const int* __restrict__ arow,
                                                 int* __restrict__ counts, int E, int B,
                                                 const float* __restrict__ w1,
                                                 const float* __restrict__ w2,
                                                 unsigned short* __restrict__ w1T,
                                                 unsigned short* __restrict__ w2T,
                                                 int* __restrict__ rowptr,
                                                 int2* __restrict__ epkS, int N) {
    const int tid = threadIdx.x;
    // ---- prep slice (first ~100 blocks' threads) ----
    int gi = blockIdx.x * 256 + tid;
    if (gi < 16384) {                       // w1T[n*128+k] = w1[k*128+n]
        int n = gi >> 7, k = gi & 127;
        w1T[gi] = f2bf(w1[k * 128 + n]);
    } else if (gi < 24576) {                // w2T[n*128+k] = w2[k*64+n]
        int i2 = gi - 16384;
        int n = i2 >> 7, k = i2 & 127;
        w2T[i2] = f2bf(w2[k * 64 + n]);
    } else if (gi < 24576 + 32) {           // sentinels for spmm overread
        epkS[E + (gi - 24576)] = make_int2(0, 0);
    } else if (gi == 24576 + 32) {
        rowptr[N] = E;
    }
    // ---- histogram ----
    __shared__ int lh[MAXB];
    for (int i = tid; i < B; i += 256) lh[i] = 0;
    __syncthreads();
    const int base = blockIdx.x * 4096;
#pragma unroll
    for (int j = 0; j < 16; ++j) {
        int i = base + j * 256 + tid;
        if (i < E) atomicAdd(&lh[arow[i] >> 7], 1);
    }
    __syncthreads();
    for (int i = tid; i < B; i += 256) {
        int c = lh[i];
        if (c) atomicAdd(&counts[i], c);
    }
}

// ---- single-block exclusive scan over bucket counts -----------------------
__global__ __launch_bounds__(256) void scan_s(const int* __restrict__ counts,
                                              int* __restrict__ boff,
                                              int* __restrict__ gcursor, int B, int E) {
    __shared__ int lds[256];
    const int t = threadIdx.x;
    const int b0 = t * 4;
    int v[4];
    int s = 0;
#pragma unroll
    for (int j = 0; j < 4; ++j) {
        v[j] = (b0 + j < B) ? counts[b0 + j] : 0;
        s += v[j];
    }
    lds[t] = s;
    __syncthreads();
    for (int off = 1; off < 256; off <<= 1) {
        int tmp = 0;
        if (t >= off) tmp = lds[t - off];
        __syncthreads();
        if (t >= off) lds[t] += tmp;
        __syncthreads();
    }
    int run = (t > 0) ? lds[t - 1] : 0;
#pragma unroll
    for (int j = 0; j < 4; ++j) {
        if (b0 + j < B) {
            boff[b0 + j] = run;
            gcursor[b0 + j] = run;
        }
        run += v[j];
    }
    if (t == 255) boff[B] = E;
}

// ---- pass 1: bucket-order edges with LDS staging (coalesced out) ----------
__global__ __launch_bounds__(256) void partition_k(const int* __restrict__ arow,
                                                   const int* __restrict__ acol,
                                                   const float* __restrict__ aval,
                                                   int* __restrict__ gcursor,
                                                   int2* __restrict__ epk, int E, int B) {
    __shared__ int2 ldata[4096];
    __shared__ int ldest[4096];
    __shared__ int lhist[MAXB];
    __shared__ int lscan[MAXB];
    __shared__ int ldelta[MAXB];
    __shared__ int lcur[MAXB];
    __shared__ int stmp[256];
    const int tid = threadIdx.x;
    const int base = blockIdx.x * 4096;
    const int cnt = min(4096, E - base);

    for (int i = tid; i < MAXB; i += 256) {
        lhist[i] = 0;
        lcur[i] = 0;
    }
    __syncthreads();

    int rr[16];
#pragma unroll
    for (int j = 0; j < 16; ++j) {
        int i = base + j * 256 + tid;
        rr[j] = (i < E) ? arow[i] : -1;
        if (rr[j] >= 0) atomicAdd(&lhist[rr[j] >> 7], 1);
    }
    __syncthreads();

    const int b0 = tid * 4;
    int v[4];
    int s = 0;
#pragma unroll
    for (int j = 0; j < 4; ++j) {
        v[j] = (b0 + j < MAXB) ? lhist[b0 + j] : 0;
        s += v[j];
    }
    stmp[tid] = s;
    __syncthreads();
    for (int off = 1; off < 256; off <<= 1) {
        int tmp = 0;
        if (tid >= off) tmp = stmp[tid - off];
        __syncthreads();
        if (tid >= off) stmp[tid] += tmp;
        __syncthreads();
    }
    int run = (tid > 0) ? stmp[tid - 1] : 0;
#pragma unroll
    for (int j = 0; j < 4; ++j) {
        if (b0 + j < MAXB) lscan[b0 + j] = run;
        run += v[j];
    }
    __syncthreads();

    for (int b = tid; b < B; b += 256) {
        int c = lhist[b];
        if (c) ldelta[b] = atomicAdd(&gcursor[b], c) - lscan[b];
    }
    __syncthreads();

#pragma unroll
    for (int j = 0; j < 16; ++j) {
        int i = base + j * 256 + tid;
        if (i < E) {
            int r = rr[j];
            int b = r >> 7;
            int lp = atomicAdd(&lcur[b], 1);
            int slot = lscan[b] + lp;
            int pk = acol[i] | ((r & 127) << 17);
            ldata[slot] = make_int2(pk, __float_as_int(aval[i]));
            ldest[slot] = ldelta[b] + slot;
        }
    }
    __syncthreads();

    for (int s2 = tid; s2 < cnt; s2 += 256) epk[ldest[s2]] = ldata[s2];
}

// ---- MFMA GEMM body (global A): y_bf16[M x NC] = A[M x 128] @ W[128 x NC] -
template <int NC, bool AF32>
__device__ __forceinline__ void gemm_body(const void* __restrict__ A,
                                          const unsigned short* __restrict__ wT,
                                          unsigned short* __restrict__ y, int M,
                                          int bid, char* smem) {
    constexpr int KP = 136;
    constexpr int NT = NC / 16;
    unsigned short* wl = (unsigned short*)smem;
    const int tid = threadIdx.x;
    for (int idx = tid; idx < NC * 16; idx += 256) {
        int n = idx >> 4, kc = idx & 15;
        *(uint4*)&wl[n * KP + kc * 8] = *(const uint4*)&wT[n * 128 + kc * 8];
    }
    __syncthreads();

    const int wave = tid >> 6;
    const int lane = tid & 63;
    const int m = lane & 15;
    const int q = lane >> 4;
    const int rowbase = bid * 64 + wave * 16;
    const int rowc = min(rowbase + m, M - 1);

    v4f acc[NT] = {};
    union LU { uint4 qv; v8bf b; };

#pragma unroll
    for (int ks = 0; ks < 4; ++ks) {
        const int k0 = ks * 32 + q * 8;
        v8bf a;
        if (AF32) {
            const float* Ap = (const float*)A + (size_t)rowc * 128 + k0;
            float4 f0 = *(const float4*)Ap;
            float4 f1 = *(const float4*)(Ap + 4);
            union { unsigned short s[8]; v8bf b; } cv;
            cv.s[0] = f2bf(f0.x); cv.s[1] = f2bf(f0.y);
            cv.s[2] = f2bf(f0.z); cv.s[3] = f2bf(f0.w);
            cv.s[4] = f2bf(f1.x); cv.s[5] = f2bf(f1.y);
            cv.s[6] = f2bf(f1.z); cv.s[7] = f2bf(f1.w);
            a = cv.b;
        } else {
            LU lu;
            lu.qv = *(const uint4*)((const unsigned short*)A + (size_t)rowc * 128 + k0);
            a = lu.b;
        }
#pragma unroll
        for (int nt = 0; nt < NT; ++nt) {
            v8bf b = *(const v8bf*)&wl[(nt * 16 + m) * KP + k0];
            acc[nt] = __builtin_amdgcn_mfma_f32_16x16x32_bf16(a, b, acc[nt], 0, 0, 0);
        }
    }
#pragma unroll
    for (int nt = 0; nt < NT; ++nt) {
#pragma unroll
        for (int r = 0; r < 4; ++r) {
            int orow = rowbase + q * 4 + r;
            if (orow < M) y[(size_t)orow * NC + nt * 16 + m] = f2bf(acc[nt][r]);
        }
    }
}

// ---- fused: bucket_sort (blocks [0,B)) || gemm1 (blocks [B, B+gb)) --------
__global__ __launch_bounds__(256) void sort_gemm1(const int* __restrict__ boff,
                                                  const int2* __restrict__ epk,
                                                  int2* __restrict__ epkS,
                                                  int* __restrict__ rowptr, int N, int B,
                                                  const float* __restrict__ x,
                                                  const unsigned short* __restrict__ w1T,
                                                  unsigned short* __restrict__ y1b) {
    __shared__ __align__(16) char smem[34816];
    const int tid = threadIdx.x;
    if (blockIdx.x >= B) {
        gemm_body<128, true>(x, w1T, y1b, N, blockIdx.x - B, smem);
        return;
    }
    // ---- bucket_sort: per-bucket LDS counting sort by local row ----
    int2* sorted = (int2*)smem;                  // 4096 * 8 = 32768
    int*  sc     = (int*)(smem + 32768);         // 128 * 4
    int*  lcur   = (int*)(smem + 32768 + 512);   // 128 * 4
    const int b = blockIdx.x;
    const int s = boff[b], e = boff[b + 1];
    const int cnt = min(e - s, 4096);
    if (tid < 128) sc[tid] = 0;
    __syncthreads();
    for (int i = s + tid; i < e; i += 256) {
        int rl = (epk[i].x >> 17) & 127;
        atomicAdd(&sc[rl], 1);
    }
    __syncthreads();
    int hv = (tid < 128) ? sc[tid] : 0;
    for (int off = 1; off < 128; off <<= 1) {
        int add = 0;
        if (tid < 128 && tid >= off) add = sc[tid - off];
        __syncthreads();
        if (tid < 128 && tid >= off) sc[tid] += add;
        __syncthreads();
    }
    if (tid < 128) {
        int ex = sc[tid] - hv;  // exclusive
        lcur[tid] = ex;
        int r = b * 128 + tid;
        if (r < N) rowptr[r] = s + ex;
    }
    __syncthreads();
    for (int i = s + tid; i < e; i += 256) {
        int2 p = epk[i];
        int rl = (p.x >> 17) & 127;
        int slot = atomicAdd(&lcur[rl], 1);
        if (slot < 4096) sorted[slot] = p;   // keep row-local bits in .x
    }
    __syncthreads();
    for (int i = tid; i < cnt; i += 256) epkS[s + i] = sorted[i];
}

// ---- reg-staged wide-gather + MFMA segmented reduction (per-wave) ---------
// NT=8: 256B rows (16 lanes/row, 4 rows/instr); NT=4: 128B (8 lanes, 8 rows).
// Body c: issue chunk c+1 gathers (cols via LDS ep stage), build val tile,
// wait vmcnt(NT), ds_write_b128 regs -> tr16 layout, tr reads, 2 MFMA/h.
// NOTE: body is a macro over NAMED register arrays gA/gB -- passing them by
// pointer (R12) made them address-taken -> scratch (VGPR=68, 504MB writes).
template <int NT>
__device__ __forceinline__ void spmm_mfma_pipe(int si, int ei, int E,
                                               const int2* __restrict__ ep,
                                               const unsigned short* __restrict__ yb,
                                               char* NB, char* AT0, char* AT1, char* epL,
                                               int lane, v4f* acc) {
    constexpr int GSH = (NT == 8) ? 4 : 3;
    constexpr int EPR = 64 >> GSH;            // k-rows covered per i-step
    constexpr int RB = NT * 32;               // bytes per y row
    const int er = lane >> GSH;
    const int oc = lane & ((1 << GSH) - 1);
    const unsigned wro = (unsigned)((oc >> 1) * 1024 + (oc & 1) * 16);
    const int q = lane >> 4, m = lane & 15;
    const int l31 = lane & 31;
    const unsigned trBo = (unsigned)(q * 256 + m * 8);
    const char* ybB = (const char*)yb;

    for (int seg = si; seg < ei; seg += 512) {
        const int segE = min(seg + 512, ei);
        const int nch = (segE - seg + 31) >> 5;
        const int nchE = (nch + 1) & ~1;      // even # bodies (extra zero-val)
        const int need = nchE * 32 + 32;      // ep slots used (<=544)
        for (int j = 0; j < 9; ++j) {
            const int idx = j * 64 + lane;
            if (idx < need) {
                const int2 t = ep[min(seg + idx, E + 31)];
                *(int2*)(epL + idx * 8) = t;
            }
        }
        uint4 gA[NT], gB[NT];

#define PIPE_ISSUE(DST, CIDX)                                                      \
        _Pragma("unroll")                                                          \
        for (int i = 0; i < NT; ++i) {                                             \
            const int2 pc = *(const int2*)(epL + ((CIDX) * 32 + i * EPR + er) * 8); \
            DST[i] = *(const uint4*)(ybB +                                         \
                        (size_t)(unsigned)(pc.x & 0x1FFFF) * RB + oc * 16);        \
        }

#define PIPE_BODY(CUR, NXT, C)                                                     \
        {                                                                          \
            PIPE_ISSUE(NXT, (C) + 1);                                              \
            __builtin_amdgcn_sched_barrier(0);                                     \
            const uint4 z4 = make_uint4(0u, 0u, 0u, 0u);                           \
            *(uint4*)(AT0 + lane * 16) = z4;                                       \
            *(uint4*)(AT1 + lane * 16) = z4;                                       \
            if (lane < 32 && seg + (C) * 32 + l31 < segE) {                        \
                const int2 pv = *(const int2*)(epL + ((C) * 32 + l31) * 8);        \
                const float v = __int_as_float(pv.y);                              \
                const unsigned short vh = f2bf(v);                                 \
                const float vhf = __uint_as_float((unsigned)vh << 16);             \
                const unsigned short vl = f2bf(v - vhf);                           \
                const int rl4 = (pv.x >> 17) & 15;                                 \
                *(unsigned short*)(AT0 + rl4 * 64 + l31 * 2) = vh;                 \
                *(unsigned short*)(AT1 + rl4 * 64 + l31 * 2) = vl;                 \
            }                                                                      \
            if constexpr (NT == 8) asm volatile("s_waitcnt vmcnt(8)" ::: "memory");\
            else                   asm volatile("s_waitcnt vmcnt(4)" ::: "memory");\
            __builtin_amdgcn_sched_barrier(0);                                     \
            _Pragma("unroll")                                                      \
            for (int i = 0; i < NT; ++i)                                           \
                *(uint4*)(NB + wro + (unsigned)((i * EPR + er) * 32)) = CUR[i];    \
            __builtin_amdgcn_sched_barrier(0);                                     \
            const unsigned trB = ldsaddr(NB) + trBo;                               \
            v2u tr0[NT], tr1[NT];                                                  \
            _Pragma("unroll")                                                      \
            for (int h = 0; h < NT; ++h) {                                         \
                tr0[h] = tr16(trB + h * 1024);                                     \
                tr1[h] = tr16(trB + h * 1024 + 128);                               \
            }                                                                      \
            const v8bf avh = *(const v8bf*)(AT0 + m * 64 + q * 16);                \
            const v8bf avl = *(const v8bf*)(AT1 + m * 64 + q * 16);                \
            asm volatile("s_waitcnt lgkmcnt(0)" ::: "memory");                     \
            __builtin_amdgcn_sched_barrier(0);                                     \
            _Pragma("unroll")                                                      \
            for (int h = 0; h < NT; ++h) {                                         \
                union { unsigned u[4]; v8bf b; } bu;                               \
                bu.u[0] = tr0[h][0]; bu.u[1] = tr0[h][1];                          \
                bu.u[2] = tr1[h][0]; bu.u[3] = tr1[h][1];                          \
                acc[h] = __builtin_amdgcn_mfma_f32_16x16x32_bf16(avh, bu.b,        \
                                                                 acc[h], 0, 0, 0); \
                acc[h] = __builtin_amdgcn_mfma_f32_16x16x32_bf16(avl, bu.b,        \
                                                                 acc[h], 0, 0, 0); \
            }                                                                      \
        }

        PIPE_ISSUE(gA, 0);
#pragma unroll 1
        for (int c = 0; c < nchE; c += 2) {
            PIPE_BODY(gA, gB, c);
            PIPE_BODY(gB, gA, c + 1);
        }
#undef PIPE_ISSUE
#undef PIPE_BODY
    }
}

// ---- fused spmm1 + gemm2: block = 2 waves x 16 rows = 32 rows -------------
__global__ __launch_bounds__(128) void spmm_gemm2(const int* __restrict__ rowptr,
                                                  const int2* __restrict__ ep,
                                                  const unsigned short* __restrict__ y1b,
                                                  const float* __restrict__ b1,
                                                  const unsigned short* __restrict__ w2T,
                                                  unsigned short* __restrict__ y2b,
                                                  int N, int E) {
    constexpr int KP = 136;
    __shared__ __align__(1024) char smem[30720];  // 2 waves * 15360
    const int tid = threadIdx.x;
    const int wave = tid >> 6, lane = tid & 63;
    char* W = smem + wave * 15360;   // NB 8K | AT0 1K | AT1 1K | epL 4.25K
    const int rowbase = blockIdx.x * 32;
    const int r0 = rowbase + wave * 16;
    const int si = __builtin_amdgcn_readfirstlane(rowptr[min(r0, N)]);
    const int ei = __builtin_amdgcn_readfirstlane(rowptr[min(r0 + 16, N)]);
    const int m = lane & 15, q = lane >> 4;

    v4f acc[8] = {};
    spmm_mfma_pipe<8>(si, ei, E, ep, y1b, W, W + 8192, W + 9216, W + 10240, lane, acc);
    __syncthreads();
    // acc -> relu+bias -> h1 (aliases staging LDS; all staging drained)
    unsigned short* h1 = (unsigned short*)smem;   // 32 rows * KP
#pragma unroll
    for (int h = 0; h < 8; ++h) {
        const float bv = b1[h * 16 + m];
#pragma unroll
        for (int r = 0; r < 4; ++r) {
            const float f = fmaxf(acc[h][r] + bv, 0.f);
            h1[(wave * 16 + q * 4 + r) * KP + h * 16 + m] = f2bf(f);
        }
    }
    __syncthreads();

    // ---- phase 2: MFMA y2 = h1 @ w2 ----
    v4f acc2[4] = {};
#pragma unroll
    for (int ks = 0; ks < 4; ++ks) {
        const int k0 = ks * 32 + q * 8;
        v8bf av = *(const v8bf*)&h1[(wave * 16 + m) * KP + k0];
#pragma unroll
        for (int nt = 0; nt < 4; ++nt) {
            v8bf b = *(const v8bf*)&w2T[(nt * 16 + m) * 128 + k0];
            acc2[nt] = __builtin_amdgcn_mfma_f32_16x16x32_bf16(av, b, acc2[nt], 0, 0, 0);
        }
    }
#pragma unroll
    for (int nt = 0; nt < 4; ++nt) {
#pragma unroll
        for (int r = 0; r < 4; ++r) {
            int orow = rowbase + wave * 16 + q * 4 + r;
            if (orow < N) y2b[(size_t)orow * 64 + nt * 16 + m] = f2bf(acc2[nt][r]);
        }
    }
}

// ---- SPMM CH=64 (layer-2 aggregate): same pipe, NT=4, f32 + bias out ------
__global__ __launch_bounds__(256) void spmm64(const int* __restrict__ rowptr,
                                              const int2* __restrict__ ep,
                                              const unsigned short* __restrict__ yb,
                                              const float* __restrict__ bias,
                                              float* __restrict__ outp, int N, int E) {
    __shared__ __align__(1024) char smem[45056];  // 4 waves * 11264
    const int tid = threadIdx.x;
    const int wave = tid >> 6, lane = tid & 63;
    char* W = smem + wave * 11264;   // NB 4K | AT0 1K | AT1 1K | epL 4.25K
    const int r0 = blockIdx.x * 64 + wave * 16;
    const int si = __builtin_amdgcn_readfirstlane(rowptr[min(r0, N)]);
    const int ei = __builtin_amdgcn_readfirstlane(rowptr[min(r0 + 16, N)]);
    const int m = lane & 15, q = lane >> 4;

    v4f acc[4] = {};
    spmm_mfma_pipe<4>(si, ei, E, ep, yb, W, W + 4096, W + 5120, W + 6144, lane, acc);

#pragma unroll
    for (int h = 0; h < 4; ++h) {
        const float bv = bias[h * 16 + m];
#pragma unroll
        for (int r = 0; r < 4; ++r) {
            const int orow = r0 + q * 4 + r;
            if (orow < N) outp[(size_t)orow * 64 + h * 16 + m] = acc[h][r] + bv;
        }
    }
}

// ---------------------------------------------------------------------------
extern "C" void kernel_launch(void* const* d_in, const int* in_sizes, int n_in,
                              void* d_out, int out_size, void* d_ws, size_t ws_size,
                              hipStream_t stream) {
    const float* x    = (const float*)d_in[0];
    const int*   arow = (const int*)d_in[1];
    const int*   acol = (const int*)d_in[2];
    const float* aval = (const float*)d_in[3];
    const float* w1   = (const float*)d_in[4];
    const float* b1   = (const float*)d_in[5];
    const float* w2   = (const float*)d_in[6];
    const float* b2   = (const float*)d_in[7];
    float*       out  = (float*)d_out;

    const int N = in_sizes[0] / 128;   // 100000
    const int E = in_sizes[1];         // 1600000
    const int B = (N + 127) >> 7;      // 782 buckets of 128 rows

    char* p = (char*)d_ws;
    auto alloc = [&](size_t bytes) {
        char* r = p;
        p += (bytes + 255) & ~(size_t)255;
        return r;
    };
    int*            counts  = (int*)alloc((size_t)MAXB * 4);
    int*            boff    = (int*)alloc((size_t)(MAXB + 1) * 4);
    int*            gcursor = (int*)alloc((size_t)MAXB * 4);
    int*            rowptr  = (int*)alloc((size_t)(N + 1) * 4);
    int2*           epkS    = (int2*)alloc((size_t)(E + 32) * 8);
    unsigned short* w1T     = (unsigned short*)alloc(128 * 128 * 2);
    unsigned short* w2T     = (unsigned short*)alloc(64 * 128 * 2);
    unsigned short* y1b     = (unsigned short*)alloc((size_t)N * 128 * 2);
    int2*           epk     = (int2*)alloc((size_t)E * 8);
    unsigned short* y2b     = (unsigned short*)alloc((size_t)N * 64 * 2);

    const int gemm_blocks = (N + 63) / 64;   // 1563
    const int pb = (E + 4095) / 4096;        // 391

    hipMemsetAsync(counts, 0, (size_t)MAXB * 4, stream);
    hist_prep<<<pb, 256, 0, stream>>>(arow, counts, E, B, w1, w2, w1T, w2T,
                                      rowptr, epkS, N);
    scan_s<<<1, 256, 0, stream>>>(counts, boff, gcursor, B, E);
    partition_k<<<pb, 256, 0, stream>>>(arow, acol, aval, gcursor, epk, E, B);
    sort_gemm1<<<B + gemm_blocks, 256, 0, stream>>>(boff, epk, epkS, rowptr, N, B,
                                                    x, w1T, y1b);
    const int sg2_blocks = (N + 31) / 32;    // 3125, 128-thread blocks
    spmm_gemm2<<<sg2_blocks, 128, 0, stream>>>(rowptr, epkS, y1b, b1, w2T, y2b, N, E);
    spmm64<<<gemm_blocks, 256, 0, stream>>>(rowptr, epkS, y2b, b2, out, N, E);
}

// Round 10
// 269.657 us; speedup vs baseline: 1.7476x; 1.7476x over previous
//
#include <hip/hip_runtime.h>

// ---------------------------------------------------------------------------
// GCN: out = spmm(A, relu(spmm(A, x)@w1 + b1)) @ w2 + b2
// Reordered: y1 = x@w1 ; h1 = relu(spmm(y1)+b1) ; y2 = h1@w2 ; out = spmm(y2)+b2
// R14 (resubmit; prior round was an infra failure, kernel never ran):
//   wide reg-staged gathers in DRAIN-MODE (R10 structure, known-clean
//   codegen). Per 32-edge chunk: 8x dwordx4 instructions (4 rows each, 128B
//   line requests, 4x fewer requests than the 32B DMA) -> ds_write_b128 into
//   the tr16 tile -> tr reads -> MFMA. g[] lives only within one body (no
//   loop-carried arrays -- R12/R13's scratch spill came from those). Only a
//   scalar int2 pe-prefetch crosses iterations (clean in R11).
// ---------------------------------------------------------------------------

typedef __bf16 v8bf __attribute__((ext_vector_type(8)));
typedef float  v4f  __attribute__((ext_vector_type(4)));
typedef unsigned v2u __attribute__((ext_vector_type(2)));

#define AS3 __attribute__((address_space(3)))

#define MAXB 800  // max buckets (N<=102400)

__device__ __forceinline__ unsigned short f2bf(float f) {
    unsigned u = __float_as_uint(f);
    unsigned r = u + 0x7fffu + ((u >> 16) & 1u);   // RNE
    return (unsigned short)(r >> 16);
}

__device__ __forceinline__ unsigned ldsaddr(const void* p) {
    return (unsigned)(unsigned long long)(const AS3 char*)p;
}

// HW transpose read (cooperative per 16-lane group): the group's 16 8-B slots
// form a 128-B 4x16 bf16 tile; lane receives column = its slot index.
__device__ __forceinline__ v2u tr16(unsigned a) {
    v2u d;
    asm volatile("ds_read_b64_tr_b16 %0, %1" : "=v"(d) : "v"(a));
    return d;
}

// ---- hist + prep: bucket histogram, weight casts, sentinels ---------------
__global__ __launch_bounds__(256) void hist_prep(const int* __restrict__ arow,
                                                 int* __restrict__ counts, int E, int B,
                                                 const float* __restrict__ w1,
                                                 const float* __restrict__ w2,
                                                 unsigned short* __restrict__ w1T,
                                                 unsigned short* __restrict__ w2T,
                                                 int* __restrict__ rowptr,
                                                 int2* __restrict__ epkS, int N) {
    const int tid = threadIdx.x;
    // ---- prep slice (first ~100 blocks' threads) ----
    int gi = blockIdx.x * 256 + tid;
    if (gi < 16384) {                       // w1T[n*128+k] = w1[k*128+n]
        int n = gi >> 7, k = gi & 127;
        w1T[gi] = f2bf(w1[k * 128 + n]);
    } else if (gi < 24576) {                // w2T[n*128+k] = w2[k*64+n]
        int i2 = gi - 16384;
        int n = i2 >> 7, k = i2 & 127;
        w2T[i2] = f2bf(w2[k * 64 + n]);
    } else if (gi < 24576 + 32) {           // sentinels for spmm overread
        epkS[E + (gi - 24576)] = make_int2(0, 0);
    } else if (gi == 24576 + 32) {
        rowptr[N] = E;
    }
    // ---- histogram ----
    __shared__ int lh[MAXB];
    for (int i = tid; i < B; i += 256) lh[i] = 0;
    __syncthreads();
    const int base = blockIdx.x * 4096;
#pragma unroll
    for (int j = 0; j < 16; ++j) {
        int i = base + j * 256 + tid;
        if (i < E) atomicAdd(&lh[arow[i] >> 7], 1);
    }
    __syncthreads();
    for (int i = tid; i < B; i += 256) {
        int c = lh[i];
        if (c) atomicAdd(&counts[i], c);
    }
}

// ---- single-block exclusive scan over bucket counts -----------------------
__global__ __launch_bounds__(256) void scan_s(const int* __restrict__ counts,
                                              int* __restrict__ boff,
                                              int* __restrict__ gcursor, int B, int E) {
    __shared__ int lds[256];
    const int t = threadIdx.x;
    const int b0 = t * 4;
    int v[4];
    int s = 0;
#pragma unroll
    for (int j = 0; j < 4; ++j) {
        v[j] = (b0 + j < B) ? counts[b0 + j] : 0;
        s += v[j];
    }
    lds[t] = s;
    __syncthreads();
    for (int off = 1; off < 256; off <<= 1) {
        int tmp = 0;
        if (t >= off) tmp = lds[t - off];
        __syncthreads();
        if (t >= off) lds[t] += tmp;
        __syncthreads();
    }
    int run = (t > 0) ? lds[t - 1] : 0;
#pragma unroll
    for (int j = 0; j < 4; ++j) {
        if (b0 + j < B) {
            boff[b0 + j] = run;
            gcursor[b0 + j] = run;
        }
        run += v[j];
    }
    if (t == 255) boff[B] = E;
}

// ---- pass 1: bucket-order edges with LDS staging (coalesced out) ----------
__global__ __launch_bounds__(256) void partition_k(const int* __restrict__ arow,
                                                   const int* __restrict__ acol,
                                                   const float* __restrict__ aval,
                                                   int* __restrict__ gcursor,
                                                   int2* __restrict__ epk, int E, int B) {
    __shared__ int2 ldata[4096];
    __shared__ int ldest[4096];
    __shared__ int lhist[MAXB];
    __shared__ int lscan[MAXB];
    __shared__ int ldelta[MAXB];
    __shared__ int lcur[MAXB];
    __shared__ int stmp[256];
    const int tid = threadIdx.x;
    const int base = blockIdx.x * 4096;
    const int cnt = min(4096, E - base);

    for (int i = tid; i < MAXB; i += 256) {
        lhist[i] = 0;
        lcur[i] = 0;
    }
    __syncthreads();

    int rr[16];
#pragma unroll
    for (int j = 0; j < 16; ++j) {
        int i = base + j * 256 + tid;
        rr[j] = (i < E) ? arow[i] : -1;
        if (rr[j] >= 0) atomicAdd(&lhist[rr[j] >> 7], 1);
    }
    __syncthreads();

    const int b0 = tid * 4;
    int v[4];
    int s = 0;
#pragma unroll
    for (int j = 0; j < 4; ++j) {
        v[j] = (b0 + j < MAXB) ? lhist[b0 + j] : 0;
        s += v[j];
    }
    stmp[tid] = s;
    __syncthreads();
    for (int off = 1; off < 256; off <<= 1) {
        int tmp = 0;
        if (tid >= off) tmp = stmp[tid - off];
        __syncthreads();
        if (tid >= off) stmp[tid] += tmp;
        __syncthreads();
    }
    int run = (tid > 0) ? stmp[tid - 1] : 0;
#pragma unroll
    for (int j = 0; j < 4; ++j) {
        if (b0 + j < MAXB) lscan[b0 + j] = run;
        run += v[j];
    }
    __syncthreads();

    for (int b = tid; b < B; b += 256) {
        int c = lhist[b];
        if (c) ldelta[b] = atomicAdd(&gcursor[b], c) - lscan[b];
    }
    __syncthreads();

#pragma unroll
    for (int j = 0; j < 16; ++j) {
        int i = base + j * 256 + tid;
        if (i < E) {
            int r = rr[j];
            int b = r >> 7;
            int lp = atomicAdd(&lcur[b], 1);
            int slot = lscan[b] + lp;
            int pk = acol[i] | ((r & 127) << 17);
            ldata[slot] = make_int2(pk, __float_as_int(aval[i]));
            ldest[slot] = ldelta[b] + slot;
        }
    }
    __syncthreads();

    for (int s2 = tid; s2 < cnt; s2 += 256) epk[ldest[s2]] = ldata[s2];
}

// ---- MFMA GEMM body (global A): y_bf16[M x NC] = A[M x 128] @ W[128 x NC] -
template <int NC, bool AF32>
__device__ __forceinline__ void gemm_body(const void* __restrict__ A,
                                          const unsigned short* __restrict__ wT,
                                          unsigned short* __restrict__ y, int M,
                                          int bid, char* smem) {
    constexpr int KP = 136;
    constexpr int NT = NC / 16;
    unsigned short* wl = (unsigned short*)smem;
    const int tid = threadIdx.x;
    for (int idx = tid; idx < NC * 16; idx += 256) {
        int n = idx >> 4, kc = idx & 15;
        *(uint4*)&wl[n * KP + kc * 8] = *(const uint4*)&wT[n * 128 + kc * 8];
    }
    __syncthreads();

    const int wave = tid >> 6;
    const int lane = tid & 63;
    const int m = lane & 15;
    const int q = lane >> 4;
    const int rowbase = bid * 64 + wave * 16;
    const int rowc = min(rowbase + m, M - 1);

    v4f acc[NT] = {};
    union LU { uint4 qv; v8bf b; };

#pragma unroll
    for (int ks = 0; ks < 4; ++ks) {
        const int k0 = ks * 32 + q * 8;
        v8bf a;
        if (AF32) {
            const float* Ap = (const float*)A + (size_t)rowc * 128 + k0;
            float4 f0 = *(const float4*)Ap;
            float4 f1 = *(const float4*)(Ap + 4);
            union { unsigned short s[8]; v8bf b; } cv;
            cv.s[0] = f2bf(f0.x); cv.s[1] = f2bf(f0.y);
            cv.s[2] = f2bf(f0.z); cv.s[3] = f2bf(f0.w);
            cv.s[4] = f2bf(f1.x); cv.s[5] = f2bf(f1.y);
            cv.s[6] = f2bf(f1.z); cv.s[7] = f2bf(f1.w);
            a = cv.b;
        } else {
            LU lu;
            lu.qv = *(const uint4*)((const unsigned short*)A + (size_t)rowc * 128 + k0);
            a = lu.b;
        }
#pragma unroll
        for (int nt = 0; nt < NT; ++nt) {
            v8bf b = *(const v8bf*)&wl[(nt * 16 + m) * KP + k0];
            acc[nt] = __builtin_amdgcn_mfma_f32_16x16x32_bf16(a, b, acc[nt], 0, 0, 0);
        }
    }
#pragma unroll
    for (int nt = 0; nt < NT; ++nt) {
#pragma unroll
        for (int r = 0; r < 4; ++r) {
            int orow = rowbase + q * 4 + r;
            if (orow < M) y[(size_t)orow * NC + nt * 16 + m] = f2bf(acc[nt][r]);
        }
    }
}

// ---- fused: bucket_sort (blocks [0,B)) || gemm1 (blocks [B, B+gb)) --------
__global__ __launch_bounds__(256) void sort_gemm1(const int* __restrict__ boff,
                                                  const int2* __restrict__ epk,
                                                  int2* __restrict__ epkS,
                                                  int* __restrict__ rowptr, int N, int B,
                                                  const float* __restrict__ x,
                                                  const unsigned short* __restrict__ w1T,
                                                  unsigned short* __restrict__ y1b) {
    __shared__ __align__(16) char smem[34816];
    const int tid = threadIdx.x;
    if (blockIdx.x >= B) {
        gemm_body<128, true>(x, w1T, y1b, N, blockIdx.x - B, smem);
        return;
    }
    // ---- bucket_sort: per-bucket LDS counting sort by local row ----
    int2* sorted = (int2*)smem;                  // 4096 * 8 = 32768
    int*  sc     = (int*)(smem + 32768);         // 128 * 4
    int*  lcur   = (int*)(smem + 32768 + 512);   // 128 * 4
    const int b = blockIdx.x;
    const int s = boff[b], e = boff[b + 1];
    const int cnt = min(e - s, 4096);
    if (tid < 128) sc[tid] = 0;
    __syncthreads();
    for (int i = s + tid; i < e; i += 256) {
        int rl = (epk[i].x >> 17) & 127;
        atomicAdd(&sc[rl], 1);
    }
    __syncthreads();
    int hv = (tid < 128) ? sc[tid] : 0;
    for (int off = 1; off < 128; off <<= 1) {
        int add = 0;
        if (tid < 128 && tid >= off) add = sc[tid - off];
        __syncthreads();
        if (tid < 128 && tid >= off) sc[tid] += add;
        __syncthreads();
    }
    if (tid < 128) {
        int ex = sc[tid] - hv;  // exclusive
        lcur[tid] = ex;
        int r = b * 128 + tid;
        if (r < N) rowptr[r] = s + ex;
    }
    __syncthreads();
    for (int i = s + tid; i < e; i += 256) {
        int2 p = epk[i];
        int rl = (p.x >> 17) & 127;
        int slot = atomicAdd(&lcur[rl], 1);
        if (slot < 4096) sorted[slot] = p;   // keep row-local bits in .x
    }
    __syncthreads();
    for (int i = tid; i < cnt; i += 256) epkS[s + i] = sorted[i];
}

// ---- wide reg-staged gather + MFMA segmented reduction (drain-mode) -------
// NT=8: 256B rows (16 lanes/row, 4 rows/instr); NT=4: 128B (8 lanes, 8 rows).
// Per chunk: 8 (NT) gather instrs -> [ds_write tiled] -> tr16 -> 2 MFMA/h.
// g[] lives only within one body (no loop-carried arrays -> no scratch).
template <int NT>
__device__ __forceinline__ void spmm_mfma_pipe(int si, int ei, int E,
                                               const int2* __restrict__ ep,
                                               const unsigned short* __restrict__ yb,
                                               char* NB, char* AT0, char* AT1,
                                               int lane, v4f* acc) {
    constexpr int GSH = (NT == 8) ? 4 : 3;
    constexpr int EPR = 64 >> GSH;            // edges covered per instruction
    constexpr int RB = NT * 32;               // bytes per y row
    const int er = lane >> GSH;
    const int oc = lane & ((1 << GSH) - 1);
    const unsigned wro = (unsigned)((oc >> 1) * 1024 + (oc & 1) * 16);
    const int q = lane >> 4, m = lane & 15;
    const int l31 = lane & 31;
    const unsigned trBo = (unsigned)(q * 256 + m * 8);
    const char* ybB = (const char*)yb;
    if (si >= ei) return;

    int2 pe = ep[min(si + l31, E + 31)];
#pragma unroll 1
    for (int cb = si; cb < ei; cb += 32) {
        // wide gathers for this chunk (cols via bpermute of pe.x)
        uint4 g[NT];
#pragma unroll
        for (int i = 0; i < NT; ++i) {
            const int cg = __shfl(pe.x, i * EPR + er) & 0x1FFFF;
            g[i] = *(const uint4*)(ybB + (size_t)(unsigned)cg * RB + oc * 16);
        }
        // prefetch next chunk's edge packets (single scalar int2, in flight)
        const int2 peN = ep[min(cb + 32 + l31, E + 31)];
        // val tile (hi+lo bf16 split) for this chunk
        const uint4 z4 = make_uint4(0u, 0u, 0u, 0u);
        *(uint4*)(AT0 + lane * 16) = z4;
        *(uint4*)(AT1 + lane * 16) = z4;
        if (lane < 32 && cb + l31 < ei) {
            const float v = __int_as_float(pe.y);
            const unsigned short vh = f2bf(v);
            const float vhf = __uint_as_float((unsigned)vh << 16);
            const unsigned short vl = f2bf(v - vhf);
            const int rl4 = (pe.x >> 17) & 15;
            *(unsigned short*)(AT0 + rl4 * 64 + l31 * 2) = vh;
            *(unsigned short*)(AT1 + rl4 * 64 + l31 * 2) = vl;
        }
        // stage regs -> tiled LDS [chhi][k][chlo16] (compiler inserts vmcnt)
#pragma unroll
        for (int i = 0; i < NT; ++i)
            *(uint4*)(NB + wro + (unsigned)((i * EPR + er) * 32)) = g[i];
        const unsigned trB = ldsaddr(NB) + trBo;
        v2u tr0[NT], tr1[NT];
#pragma unroll
        for (int h = 0; h < NT; ++h) {
            tr0[h] = tr16(trB + h * 1024);
            tr1[h] = tr16(trB + h * 1024 + 128);
        }
        const v8bf avh = *(const v8bf*)(AT0 + m * 64 + q * 16);
        const v8bf avl = *(const v8bf*)(AT1 + m * 64 + q * 16);
        asm volatile("s_waitcnt lgkmcnt(0)" ::: "memory");
        __builtin_amdgcn_sched_barrier(0);
#pragma unroll
        for (int h = 0; h < NT; ++h) {
            union { unsigned u[4]; v8bf b; } bu;
            bu.u[0] = tr0[h][0]; bu.u[1] = tr0[h][1];
            bu.u[2] = tr1[h][0]; bu.u[3] = tr1[h][1];
            acc[h] = __builtin_amdgcn_mfma_f32_16x16x32_bf16(avh, bu.b, acc[h], 0, 0, 0);
            acc[h] = __builtin_amdgcn_mfma_f32_16x16x32_bf16(avl, bu.b, acc[h], 0, 0, 0);
        }
        pe = peN;
    }
}

// ---- fused spmm1 + gemm2: block = 2 waves x 16 rows = 32 rows -------------
__global__ __launch_bounds__(128) void spmm_gemm2(const int* __restrict__ rowptr,
                                                  const int2* __restrict__ ep,
                                                  const unsigned short* __restrict__ y1b,
                                                  const float* __restrict__ b1,
                                                  const unsigned short* __restrict__ w2T,
                                                  unsigned short* __restrict__ y2b,
                                                  int N, int E) {
    constexpr int KP = 136;
    __shared__ __align__(1024) char smem[20480];  // 2 waves * (8K NB + 2x1K AT)
    const int tid = threadIdx.x;
    const int wave = tid >> 6, lane = tid & 63;
    char* W = smem + wave * 10240;
    const int rowbase = blockIdx.x * 32;
    const int r0 = rowbase + wave * 16;
    const int si = __builtin_amdgcn_readfirstlane(rowptr[min(r0, N)]);
    const int ei = __builtin_amdgcn_readfirstlane(rowptr[min(r0 + 16, N)]);
    const int m = lane & 15, q = lane >> 4;

    v4f acc[8] = {};
    spmm_mfma_pipe<8>(si, ei, E, ep, y1b, W, W + 8192, W + 9216, lane, acc);
    __syncthreads();
    // acc -> relu+bias -> h1 (aliases staging LDS; all staging drained)
    unsigned short* h1 = (unsigned short*)smem;   // 32 rows * KP = 8704 B
#pragma unroll
    for (int h = 0; h < 8; ++h) {
        const float bv = b1[h * 16 + m];
#pragma unroll
        for (int r = 0; r < 4; ++r) {
            const float f = fmaxf(acc[h][r] + bv, 0.f);
            h1[(wave * 16 + q * 4 + r) * KP + h * 16 + m] = f2bf(f);
        }
    }
    __syncthreads();

    // ---- phase 2: MFMA y2 = h1 @ w2 ----
    v4f acc2[4] = {};
#pragma unroll
    for (int ks = 0; ks < 4; ++ks) {
        const int k0 = ks * 32 + q * 8;
        v8bf av = *(const v8bf*)&h1[(wave * 16 + m) * KP + k0];
#pragma unroll
        for (int nt = 0; nt < 4; ++nt) {
            v8bf b = *(const v8bf*)&w2T[(nt * 16 + m) * 128 + k0];
            acc2[nt] = __builtin_amdgcn_mfma_f32_16x16x32_bf16(av, b, acc2[nt], 0, 0, 0);
        }
    }
#pragma unroll
    for (int nt = 0; nt < 4; ++nt) {
#pragma unroll
        for (int r = 0; r < 4; ++r) {
            int orow = rowbase + wave * 16 + q * 4 + r;
            if (orow < N) y2b[(size_t)orow * 64 + nt * 16 + m] = f2bf(acc2[nt][r]);
        }
    }
}

// ---- SPMM CH=64 (layer-2 aggregate): same pipe, NT=4, f32 + bias out ------
__global__ __launch_bounds__(256) void spmm64(const int* __restrict__ rowptr,
                                              const int2* __restrict__ ep,
                                              const unsigned short* __restrict__ yb,
                                              const float* __restrict__ bias,
                                              float* __restrict__ outp, int N, int E) {
    __shared__ __align__(1024) char smem[24576];  // 4 waves * (4K NB + 2x1K AT)
    const int tid = threadIdx.x;
    const int wave = tid >> 6, lane = tid & 63;
    char* W = smem + wave * 6144;
    const int r0 = blockIdx.x * 64 + wave * 16;
    const int si = __builtin_amdgcn_readfirstlane(rowptr[min(r0, N)]);
    const int ei = __builtin_amdgcn_readfirstlane(rowptr[min(r0 + 16, N)]);
    const int m = lane & 15, q = lane >> 4;

    v4f acc[4] = {};
    spmm_mfma_pipe<4>(si, ei, E, ep, yb, W, W + 4096, W + 5120, lane, acc);

#pragma unroll
    for (int h = 0; h < 4; ++h) {
        const float bv = bias[h * 16 + m];
#pragma unroll
        for (int r = 0; r < 4; ++r) {
            const int orow = r0 + q * 4 + r;
            if (orow < N) outp[(size_t)orow * 64 + h * 16 + m] = acc[h][r] + bv;
        }
    }
}

// ---------------------------------------------------------------------------
extern "C" void kernel_launch(void* const* d_in, const int* in_sizes, int n_in,
                              void* d_out, int out_size, void* d_ws, size_t ws_size,
                              hipStream_t stream) {
    const float* x    = (const float*)d_in[0];
    const int*   arow = (const int*)d_in[1];
    const int*   acol = (const int*)d_in[2];
    const float* aval = (const float*)d_in[3];
    const float* w1   = (const float*)d_in[4];
    const float* b1   = (const float*)d_in[5];
    const float* w2   = (const float*)d_in[6];
    const float* b2   = (const float*)d_in[7];
    float*       out  = (float*)d_out;

    const int N = in_sizes[0] / 128;   // 100000
    const int E = in_sizes[1];         // 1600000
    const int B = (N + 127) >> 7;      // 782 buckets of 128 rows

    char* p = (char*)d_ws;
    auto alloc = [&](size_t bytes) {
        char* r = p;
        p += (bytes + 255) & ~(size_t)255;
        return r;
    };
    int*            counts  = (int*)alloc((size_t)MAXB * 4);
    int*            boff    = (int*)alloc((size_t)(MAXB + 1) * 4);
    int*            gcursor = (int*)alloc((size_t)MAXB * 4);
    int*            rowptr  = (int*)alloc((size_t)(N + 1) * 4);
    int2*           epkS    = (int2*)alloc((size_t)(E + 32) * 8);
    unsigned short* w1T     = (unsigned short*)alloc(128 * 128 * 2);
    unsigned short* w2T     = (unsigned short*)alloc(64 * 128 * 2);
    unsigned short* y1b     = (unsigned short*)alloc((size_t)N * 128 * 2);
    int2*           epk     = (int2*)alloc((size_t)E * 8);
    unsigned short* y2b     = (unsigned short*)alloc((size_t)N * 64 * 2);

    const int gemm_blocks = (N + 63) / 64;   // 1563
    const int pb = (E + 4095) / 4096;        // 391

    hipMemsetAsync(counts, 0, (size_t)MAXB * 4, stream);
    hist_prep<<<pb, 256, 0, stream>>>(arow, counts, E, B, w1, w2, w1T, w2T,
                                      rowptr, epkS, N);
    scan_s<<<1, 256, 0, stream>>>(counts, boff, gcursor, B, E);
    partition_k<<<pb, 256, 0, stream>>>(arow, acol, aval, gcursor, epk, E, B);
    sort_gemm1<<<B + gemm_blocks, 256, 0, stream>>>(boff, epk, epkS, rowptr, N, B,
                                                    x, w1T, y1b);
    const int sg2_blocks = (N + 31) / 32;    // 3125, 128-thread blocks
    spmm_gemm2<<<sg2_blocks, 128, 0, stream>>>(rowptr, epkS, y1b, b1, w2T, y2b, N, E);
    spmm64<<<gemm_blocks, 256, 0, stream>>>(rowptr, epkS, y2b, b2, out, N, E);
}